// Round 8
// baseline (1078.733 us; speedup 1.0000x reference)
//
#include <hip/hip_runtime.h>
#include <hip/hip_bf16.h>

#define HH 192
#define WW 192
#define HW (HH*WW)

typedef unsigned short u16;
typedef __attribute__((ext_vector_type(8))) short short8;
typedef __attribute__((ext_vector_type(16))) float float16;

__device__ __forceinline__ float b2f(u16 u){
  union { unsigned int i; float f; } v; v.i = ((unsigned int)u) << 16; return v.f;
}
__device__ __forceinline__ u16 f2b(float f){
  union { unsigned int i; float f; } v; v.f = f;
  unsigned int r = v.i + 0x7FFFu + ((v.i >> 16) & 1u);
  return (u16)(r >> 16);
}
__device__ __forceinline__ void up2(unsigned int w, float& lo, float& hi){
  union { unsigned int i; float f; } a, b;
  a.i = w << 16; b.i = w & 0xFFFF0000u;
  lo = a.f; hi = b.f;
}
__device__ __forceinline__ float lrelu(float x){ return x >= 0.f ? x : 0.1f*x; }
__device__ __forceinline__ float ldmix(const void* p, int i, bool bf){
  return bf ? b2f(((const u16*)p)[i]) : ((const float*)p)[i];
}

using bf2 = __attribute__((ext_vector_type(2))) __bf16;
__device__ __forceinline__ float dot2bf(unsigned int a, unsigned int b, float c){
#if __has_builtin(__builtin_amdgcn_fdot2_f32_bf16)
  union { unsigned int u; bf2 v; } ua, ub; ua.u = a; ub.u = b;
  return __builtin_amdgcn_fdot2_f32_bf16(ua.v, ub.v, c, false);
#else
  float al,ah,bl,bh; up2(a,al,ah); up2(b,bl,bh);
  return c + al*bl + ah*bh;
#endif
}

__global__ __launch_bounds__(256) void detect_k(const unsigned int* __restrict__ w, int* __restrict__ flag){
  __shared__ int cnt;
  if (threadIdx.x == 0) cnt = 0;
  __syncthreads();
  unsigned int v = w[(size_t)threadIdx.x * 1024];
  int e = (v >> 7) & 0xFF;
  bool ok = ((v & 0xFFFFu) == 0u) || (e > 100 && e < 150);
  if (ok) atomicAdd(&cnt, 1);
  __syncthreads();
  if (threadIdx.x == 0) *flag = (cnt >= 192) ? 1 : 0;
}

// NCHW (fp32 or bf16) -> NHWC bf16 [8][HW][64] via LDS transpose tile.
__global__ __launch_bounds__(256) void cvt_t(const void* __restrict__ pred, const void* __restrict__ refp,
                                             u16* __restrict__ X1, const int* __restrict__ flag){
  __shared__ u16 t[64*72];
  int tid = threadIdx.x;
  int px0 = blockIdx.x*64, img = blockIdx.y;
  bool bf = (*flag != 0);
  const void* src = (img < 4) ? pred : refp;
  int im = (img < 4) ? img : img - 4;
  for (int e = tid; e < 4096; e += 256){
    int ch = e >> 6, px = e & 63;
    t[px*72 + ch] = f2b(ldmix(src, (im*64 + ch)*HW + px0 + px, bf));
  }
  __syncthreads();
  int px = tid >> 2, q = tid & 3;
  uint4 v0 = *(const uint4*)(t + px*72 + q*16);
  uint4 v1 = *(const uint4*)(t + px*72 + q*16 + 8);
  u16* dst = X1 + ((size_t)img*HW + px0 + px)*64 + q*16;
  *(uint4*)dst = v0;
  *(uint4*)(dst + 8) = v1;
}

__global__ __launch_bounds__(256) void prep_w(const void* __restrict__ w1, const void* __restrict__ w2,
                                              const void* __restrict__ wr, const void* __restrict__ wp,
                                              const void* __restrict__ b1, const void* __restrict__ b2,
                                              const void* __restrict__ rb,
                                              u16* __restrict__ w1m, u16* __restrict__ w2m,
                                              float* __restrict__ wrf, unsigned int* __restrict__ wpb,
                                              float* __restrict__ b1f, float* __restrict__ b2f,
                                              float* __restrict__ rbf, const int* __restrict__ flag){
  int i = blockIdx.x*256 + threadIdx.x;
  bool bf = (*flag != 0);
  if (i < 36864){
    int j = i & 7, lane = (i>>3) & 63, cot = (i>>9) & 1, ks = (i>>10) & 3, tap = i >> 12;
    int co = cot*32 + (lane & 31), ci = ks*16 + (lane>>5)*8 + j;
    w1m[i] = f2b(ldmix(w1, (co*64 + ci)*9 + tap, bf));
  }
  if (i < 73728){
    int j = i & 7, lane = (i>>3) & 63, cot = (i>>9) & 3, ks = (i>>11) & 3, tap = i >> 13;
    int co = cot*32 + (lane & 31), ci = ks*16 + (lane>>5)*8 + j;
    w2m[i] = f2b(ldmix(w2, (co*64 + ci)*9 + tap, bf));
  }
  if (i < 4096){ int co = i & 31; int ci = i >> 5;
    wrf[ci*32+co] = ldmix(wr, co*128+ci, bf); }
  if (i < 4266){
    int cp = i/18; int rr = i - cp*18; int tap = rr >> 1; int o = rr & 1;
    int c0 = 2*cp, c1 = c0 + 1;
    float f0 = ldmix(wp, (o*473+c0)*9+tap, bf);
    float f1 = (c1 < 473) ? ldmix(wp, (o*473+c1)*9+tap, bf) : 0.f;
    wpb[i] = (unsigned int)f2b(f0) | ((unsigned int)f2b(f1) << 16);
  }
  if (i < 64)  b1f[i] = ldmix(b1, i, bf);
  if (i < 128) b2f[i] = ldmix(b2, i, bf);
  if (i < 32)  rbf[i] = ldmix(rb, i, bf);
}

// MFMA implicit-GEMM 3x3 conv (see round 7).
template<int WCO>
__global__ __launch_bounds__(WCO*128) void conv_mfma(const u16* __restrict__ in, const u16* __restrict__ wm,
                                                     const float* __restrict__ bias, u16* __restrict__ out){
  constexpr int COUT = WCO*64;
  constexpr int NCOT = WCO*2;
  constexpr int THREADS = WCO*128;
  constexpr int CO_PAD = COUT + 8;
  constexpr int SLAB = 6*34*72;
  constexpr int OT   = 128*CO_PAD;
  __shared__ __align__(16) u16 smem[(SLAB > OT) ? SLAB : OT];

  int tid = threadIdx.x, lane = tid & 63, w = tid >> 6;
  int wr = w & 1, wc = w >> 1;
  int n = lane & 31, kh = lane >> 5;
  int x0 = blockIdx.x*32, y0 = blockIdx.y*4, img = blockIdx.z;
  const u16* inb = in + (size_t)img*HW*64;

  float16 acc[2][2];
  #pragma unroll
  for (int t=0;t<2;t++)
    #pragma unroll
    for (int c=0;c<2;c++)
      #pragma unroll
      for (int k=0;k<16;k++) acc[t][c][k] = 0.f;

  for (int e = tid; e < 1632; e += THREADS){
    int c8 = e & 7; int pp = e >> 3;
    int row = pp / 34, pos = pp - row*34;
    int gy = y0 + row - 1, gx = x0 + pos - 1;
    uint4 v = make_uint4(0,0,0,0);
    if (gy >= 0 && gy < HH && gx >= 0 && gx < WW)
      v = *(const uint4*)(inb + ((size_t)gy*WW + gx)*64 + c8*8);
    *(uint4*)(smem + pp*72 + c8*8) = v;
  }
  __syncthreads();

  union AU { uint4 q; short8 s; };
  union BU { uint2 u[2]; short8 s; };

  #pragma unroll 1
  for (int ky = 0; ky < 3; ++ky){
    #pragma unroll 1
    for (int kx = 0; kx < 3; ++kx){
      int tap = ky*3 + kx;
      #pragma unroll
      for (int ks = 0; ks < 4; ++ks){
        AU a0, a1;
        const u16* wmp = wm + (((size_t)(tap*4 + ks)*NCOT + wc*2)*64 + lane)*8;
        a0.q = *(const uint4*)(wmp);
        a1.q = *(const uint4*)(wmp + 512);
        #pragma unroll
        for (int t = 0; t < 2; ++t){
          int row = wr*2 + t + ky;
          int off = (row*34 + n + kx)*72 + ks*16 + kh*8;
          BU b;
          b.u[0] = *(const uint2*)(smem + off);
          b.u[1] = *(const uint2*)(smem + off + 4);
          acc[t][0] = __builtin_amdgcn_mfma_f32_32x32x16_bf16(a0.s, b.s, acc[t][0], 0, 0, 0);
          acc[t][1] = __builtin_amdgcn_mfma_f32_32x32x16_bf16(a1.s, b.s, acc[t][1], 0, 0, 0);
        }
      }
    }
  }

  __syncthreads();
  #pragma unroll
  for (int t = 0; t < 2; ++t){
    int pxl = (wr*2 + t)*32 + n;
    #pragma unroll
    for (int c = 0; c < 2; ++c){
      int cob = wc*64 + c*32 + 4*kh;
      #pragma unroll
      for (int p = 0; p < 8; ++p){
        int co = cob + (p&1)*2 + (p>>1)*8;
        float2 bb = *(const float2*)(bias + co);
        float v0 = lrelu(acc[t][c][2*p]   + bb.x);
        float v1 = lrelu(acc[t][c][2*p+1] + bb.y);
        unsigned int pk = (unsigned int)f2b(v0) | ((unsigned int)f2b(v1) << 16);
        *(unsigned int*)(smem + pxl*CO_PAD + co) = pk;
      }
    }
  }
  __syncthreads();
  int px, part;
  if (WCO == 2){ px = tid >> 1; part = tid & 1; } else { px = tid; part = 0; }
  const u16* sp = smem + px*CO_PAD + part*64;
  u16* gp = out + ((size_t)img*HW + (size_t)(y0 + (px>>5))*WW + x0 + (px&31))*COUT + part*64;
  #pragma unroll
  for (int k = 0; k < 8; ++k)
    *(uint4*)(gp + k*8) = *(const uint4*)(sp + k*8);
}

// 1x1 redir conv (128->32) + bias + lrelu. X NCHW [b][473][HW]; planes 0..31.
__global__ __launch_bounds__(256) void redir_k(const u16* __restrict__ C2, const float* __restrict__ wrf,
                                               const float* __restrict__ rbf, u16* __restrict__ X){
  int p = blockIdx.x*256 + threadIdx.x;
  int b = p / HW; int pix = p - b*HW;
  const u16* ap = C2 + (size_t)p*128;
  float acc[32];
  #pragma unroll
  for (int j=0;j<32;j++) acc[j]=0.f;
  for (int ci=0; ci<128; ci+=4){
    uint2 aw = *(const uint2*)(ap + ci);
    float a0,a1,a2,a3;
    up2(aw.x,a0,a1); up2(aw.y,a2,a3);
    const float* w0 = wrf + ci*32;
    #pragma unroll
    for (int co=0; co<32; co+=4){
      float4 wv0 = *(const float4*)(w0+co);
      float4 wv1 = *(const float4*)(w0+32+co);
      float4 wv2 = *(const float4*)(w0+64+co);
      float4 wv3 = *(const float4*)(w0+96+co);
      acc[co+0] += a0*wv0.x + a1*wv1.x + a2*wv2.x + a3*wv3.x;
      acc[co+1] += a0*wv0.y + a1*wv1.y + a2*wv2.y + a3*wv3.y;
      acc[co+2] += a0*wv0.z + a1*wv1.z + a2*wv2.z + a3*wv3.z;
      acc[co+3] += a0*wv0.w + a1*wv1.w + a2*wv2.w + a3*wv3.w;
    }
  }
  #pragma unroll
  for (int co=0; co<32; ++co){
    X[(size_t)(b*473 + co)*HW + pix] = f2b(lrelu(acc[co] + rbf[co]));
  }
}

// Correlation v5. Block = (tile k, parity, b): rows {y0, y0+2}, y0 = 4k+parity.
// 192 thr = 2 row-slots x 96 px-pairs (x, x+2). dy loop inside: rows r, r+2
// staged per dy -> dy+1 re-stages r+2 (L2-hot, same XCD) => TCC fetch ~halved.
// 2-px sharing: one staged pos feeds px-x@dx and px-x+2@dx-1 => 8.4 b128/out.
// Bank fix for stride-4 pair lanes: XOR swizzle sigma(pos)=pos^((pos>>3)&7),
// pos dim padded to 240 (sigma range) => worst 2-way conflicts.
__global__ __launch_bounds__(192,2) void corr_k(const u16* __restrict__ C2, u16* __restrict__ X){
  __shared__ __align__(16) uint4 s_seg[2][8][240];
  int tid = threadIdx.x;
  int s = (tid >= 96) ? 1 : 0;
  int j = tid - 96*s;
  int x = 4*(j>>1) + (j&1);
  int y0 = 4*blockIdx.x + blockIdx.y;
  int y  = y0 + 2*s;
  int b  = blockIdx.z;
  const u16* predb = C2 + (size_t)b*HW*128;
  const u16* refb  = C2 + (size_t)(b+4)*HW*128;

  for (int dy = 0; dy < 21; ++dy){
    int r0 = y0 + 2*dy - 20;
    float acc0[21], acc1[21];
    #pragma unroll
    for (int i=0;i<21;i++){ acc0[i]=0.f; acc1[i]=0.f; }

    for (int h = 0; h < 2; ++h){
      __syncthreads();
      // stage rows r0 (slot0), r0+2 (slot1), 64-ch half h
      for (int e = tid; e < 3728; e += 192){
        int se = (e >= 1864) ? 1 : 0;
        int rem = e - 1864*se;
        int g = rem / 233, pos = rem - g*233;
        int rr = r0 + 2*se, gx = pos - 20;
        uint4 v = make_uint4(0,0,0,0);
        if (rr >= 0 && rr < HH && gx >= 0 && gx < WW)
          v = *(const uint4*)(refb + ((size_t)rr*WW + gx)*128 + h*64 + g*8);
        int sg = pos ^ ((pos>>3)&7);
        s_seg[se][g][sg] = v;
      }
      __syncthreads();
      // pred fragments for px x and x+2 (L1-hot after first dy)
      uint4 av1[8], av2[8];
      const u16* a1 = predb + ((size_t)y*WW + x)*128 + h*64;
      const u16* a2 = a1 + 2*128;
      #pragma unroll
      for (int g=0; g<8; ++g){
        av1[g] = *(const uint4*)(a1 + g*8);
        av2[g] = *(const uint4*)(a2 + g*8);
      }
      #pragma unroll
      for (int dxe = 0; dxe < 22; ++dxe){
        int q = x + 2*dxe;
        int sq = q ^ ((q>>3)&7);
        uint4 bv[8];
        #pragma unroll
        for (int g=0; g<8; ++g) bv[g] = s_seg[s][g][sq];
        if (dxe < 21){
          float a = acc0[dxe];
          #pragma unroll
          for (int g=0; g<8; ++g){
            a = dot2bf(av1[g].x, bv[g].x, a);
            a = dot2bf(av1[g].y, bv[g].y, a);
            a = dot2bf(av1[g].z, bv[g].z, a);
            a = dot2bf(av1[g].w, bv[g].w, a);
          }
          acc0[dxe] = a;
        }
        if (dxe > 0){
          float a = acc1[dxe-1];
          #pragma unroll
          for (int g=0; g<8; ++g){
            a = dot2bf(av2[g].x, bv[g].x, a);
            a = dot2bf(av2[g].y, bv[g].y, a);
            a = dot2bf(av2[g].z, bv[g].z, a);
            a = dot2bf(av2[g].w, bv[g].w, a);
          }
          acc1[dxe-1] = a;
        }
      }
    }
    // write 21 dx for px x and x+2 (NCHW planes)
    u16* bp = X + ((size_t)(b*473 + 32 + dy*21)*HH + y)*WW;
    #pragma unroll
    for (int dx=0; dx<21; ++dx){
      bp[(size_t)dx*HW + x]   = f2b(lrelu(acc0[dx]*(1.f/128.f)));
      bp[(size_t)dx*HW + x+2] = f2b(lrelu(acc1[dx]*(1.f/128.f)));
    }
  }
}

// Final 3x3 conv: contribution-passing (see round 6).
__global__ __launch_bounds__(192) void final_k(const u16* __restrict__ X, const unsigned int* __restrict__ wpb,
                                               void* __restrict__ out, const int* __restrict__ flag){
  __shared__ float eR[4][2], eL[4][2];
  int x = threadIdx.x, y = blockIdx.x, b = blockIdx.y;
  int w = x >> 6, lane = x & 63;
  const u16* Xb = X + (size_t)b*473*HW;
  float Pm0=0.f,Pm1=0.f,Pl0=0.f,Pl1=0.f,Pr0=0.f,Pr1=0.f;
  bool rok0 = (y > 0), rok2 = (y < HH-1);
  size_t off0 = (size_t)(y-1)*WW + x;
  size_t off1 = (size_t)(y  )*WW + x;
  size_t off2 = (size_t)(y+1)*WW + x;

  for (int cp = 0; cp < 237; ++cp){
    const unsigned int* w18 = wpb + cp*18;
    size_t base0 = (size_t)(2*cp)*HW;
    size_t base1 = base0 + HW;
    bool c1ok = (2*cp+1) < 473;
    #pragma unroll
    for (int r = 0; r < 3; ++r){
      bool ok = (r==0) ? rok0 : ((r==2) ? rok2 : true);
      size_t off = (r==0) ? off0 : ((r==2) ? off2 : off1);
      unsigned int v = 0;
      if (ok){
        unsigned int lo = Xb[base0 + off];
        unsigned int hi = c1ok ? (unsigned int)Xb[base1 + off] : 0u;
        v = lo | (hi << 16);
      }
      Pm0 = dot2bf(v, w18[(r*3+1)*2+0], Pm0);
      Pm1 = dot2bf(v, w18[(r*3+1)*2+1], Pm1);
      Pl0 = dot2bf(v, w18[(r*3+2)*2+0], Pl0);
      Pl1 = dot2bf(v, w18[(r*3+2)*2+1], Pl1);
      Pr0 = dot2bf(v, w18[(r*3+0)*2+0], Pr0);
      Pr1 = dot2bf(v, w18[(r*3+0)*2+1], Pr1);
    }
  }

  float r0 = __shfl_up(Pr0,1), r1 = __shfl_up(Pr1,1);
  float l0 = __shfl_down(Pl0,1), l1 = __shfl_down(Pl1,1);
  if (x == 0){ eR[0][0]=0.f; eR[0][1]=0.f; eL[3][0]=0.f; eL[3][1]=0.f; }
  if (lane == 63){ eR[w+1][0]=Pr0; eR[w+1][1]=Pr1; }
  if (lane == 0 && w > 0){ eL[w][0]=Pl0; eL[w][1]=Pl1; }
  __syncthreads();
  if (lane == 0){ r0 = eR[w][0]; r1 = eR[w][1]; }
  if (lane == 63){ l0 = eL[w+1][0]; l1 = eL[w+1][1]; }
  float a0 = Pm0 + r0 + l0;
  float a1 = Pm1 + r1 + l1;

  size_t rem = (size_t)y*WW + x;
  size_t i0 = (size_t)(b*2)*HW + rem;
  size_t i1 = (size_t)(b*2+1)*HW + rem;
  if (*flag){
    ((u16*)out)[i0] = f2b(a0);
    ((u16*)out)[i1] = f2b(a1);
  } else {
    ((float*)out)[i0] = a0;
    ((float*)out)[i1] = a1;
  }
}

// Workspace (bytes): same as round 7.
extern "C" void kernel_launch(void* const* d_in, const int* in_sizes, int n_in,
                              void* d_out, int out_size, void* d_ws, size_t ws_size,
                              hipStream_t stream){
  char* ws = (char*)d_ws;
  u16* C2 = (u16*)ws;
  u16* X1 = (u16*)(ws + 75497472);
  u16* H1 = (u16*)(ws + 113246208);
  u16* X  = (u16*)(ws + 75497472);
  u16* w1m = (u16*)(ws + 215322624);
  u16* w2m = w1m + 36864;
  float* wrf = (float*)(w2m + 73728);
  unsigned int* wpb = (unsigned int*)(wrf + 4096);
  float* b1f = (float*)(wpb + 4266);
  float* b2f = b1f + 64;
  float* rbf = b2f + 128;
  int* flag  = (int*)(rbf + 32);

  detect_k<<<1,256,0,stream>>>((const unsigned int*)d_in[0], flag);
  cvt_t<<<dim3(576,8),256,0,stream>>>(d_in[0], d_in[1], X1, flag);
  prep_w<<<288,256,0,stream>>>(d_in[2], d_in[4], d_in[6], d_in[8],
                               d_in[3], d_in[5], d_in[7],
                               w1m, w2m, wrf, wpb, b1f, b2f, rbf, flag);
  conv_mfma<1><<<dim3(6,48,8),128,0,stream>>>(X1, w1m, b1f, H1);
  conv_mfma<2><<<dim3(6,48,8),256,0,stream>>>(H1, w2m, b2f, C2);
  redir_k<<<576,256,0,stream>>>(C2, wrf, rbf, X);
  corr_k<<<dim3(48,2,4),192,0,stream>>>(C2, X);
  final_k<<<dim3(192,4),192,0,stream>>>(X, wpb, d_out, flag);
}